// Round 7
// baseline (83.224 us; speedup 1.0000x reference)
//
#include <hip/hip_runtime.h>

// StateSpaceLayer: out[b,t,r,c] = sum_{j<=t} A[r]^(t-j) * x[b,j,r,c]
// == linear recurrence out[t] = A[r]*out[t-1] + x[t] along seq.
// Shapes: x (4,512,64,64) f32, A (64,) f32, out (4,512,64,64) f32.
//
// V7: V6b + wave-parallel Kogge-Stone carry scan.
//   Model: dur_us = kernel + ~65us fixed harness overhead. V6b kernel
//   ~17us vs 10.6us one-pass floor. The gap's biggest identified piece:
//   phase 2's serial Horner — thread ch runs ch iterations of
//   {ds_read_b128; waitcnt; 4 fmaf} (runtime trip count, no unroll),
//   ~120cyc/iter * 63 ~= 3us of pure LDS latency for the last waves.
//   Fix: 64 chunks == 64 lanes, 16 waves == 16 float4-columns. Wave w
//   scans column w across chunks IN REGISTERS with 6 __shfl_up steps
//   (weights aL^(2^s) by repeated squaring; a is block-uniform).
//   Serial depth 63 -> 6. LDS tile padded [64][17] so the column-major
//   scan read is 8-way instead of 32-way conflicted.
//   Cross-block carry schemes remain dead ends (V3 coop +200us,
//   V4 3-kernel gaps, V5 flag-spin +140us): single kernel, LDS carries.

#define B_    4
#define SEQ_  512
#define D_    64
#define CH_   8                  // timesteps per thread
#define NCH_  (SEQ_ / CH_)       // 64 chunks == 64 lanes
#define NCQ_  (D_ / 4)           // 16 float4 columns == 16 waves
#define NTHR_ (NCH_ * NCQ_)      // 1024 threads per block
#define PAD_  (NCQ_ + 1)         // 17: breaks column-read bank conflicts

typedef float f32x4 __attribute__((ext_vector_type(4)));

__global__ __launch_bounds__(NTHR_, 1) void ssm_scan_kernel(
    const float* __restrict__ x, const float* __restrict__ A,
    float* __restrict__ out)
{
    __shared__ float4 Epad[NCH_][PAD_];   // 17 KB: chunk-end states (padded)

    const int blk = blockIdx.x;          // 0 .. B_*D_-1
    const int bi  = blk >> 6;            // batch index
    const int r   = blk & 63;            // row (decay) index
    const int tid = threadIdx.x;
    const int ch  = tid >> 4;            // chunk id 0..63
    const int cq  = tid & 15;            // float4 column 0..15

    const float a = fmaxf(A[r], 1e-6f);  // clip like reference (EPS=1e-6)

    const int j0 = ch * CH_;
    // flat float index of x[bi, j0, r, cq*4]
    const size_t base = ((size_t)(bi * SEQ_ + j0) * D_ + r) * D_ + cq * 4;
    const float4* xp = (const float4*)(x + base);
    f32x4*        op = (f32x4*)(out + base);
    const int jstride4 = (D_ * D_) / 4;  // 1024 float4 between timesteps

    // Phase 1: local scan of this chunk with zero initial state.
    float4 loc[CH_];
    float s0 = 0.f, s1 = 0.f, s2 = 0.f, s3 = 0.f;
    #pragma unroll
    for (int t = 0; t < CH_; ++t) {
        float4 v = xp[(size_t)t * jstride4];
        s0 = fmaf(s0, a, v.x);
        s1 = fmaf(s1, a, v.y);
        s2 = fmaf(s2, a, v.z);
        s3 = fmaf(s3, a, v.w);
        loc[t] = make_float4(s0, s1, s2, s3);
    }

    // Keep scan results pinned in VGPRs through the barriers.
    #pragma unroll
    for (int t = 0; t < CH_; ++t) {
        asm volatile("" : "+v"(loc[t].x), "+v"(loc[t].y),
                         "+v"(loc[t].z), "+v"(loc[t].w));
    }

    // Publish chunk-end state.
    Epad[ch][cq] = make_float4(s0, s1, s2, s3);
    __syncthreads();

    // a^CH_ (= a^8) via 3 squarings.
    const float a2 = a * a, a4 = a2 * a2, aL = a4 * a4;

    // Phase 2: wave-parallel weighted Kogge-Stone inclusive scan.
    // Wave w owns float4-column cq=w; lane m owns chunk m.
    //   I_m = E_m + aL * I_{m-1}  computed in 6 shuffle steps:
    //   step s: I_m += aL^(2^s) * I_{m - 2^s}   (for m >= 2^s)
    {
        const int w = tid >> 6;          // wave id == column it scans
        const int m = tid & 63;          // lane  == chunk index
        float4 v = Epad[m][w];
        float aw = aL;
        #pragma unroll
        for (int s = 0; s < 6; ++s) {
            const int d = 1 << s;
            float ux = __shfl_up(v.x, d, 64);
            float uy = __shfl_up(v.y, d, 64);
            float uz = __shfl_up(v.z, d, 64);
            float uw = __shfl_up(v.w, d, 64);
            if (m >= d) {
                v.x = fmaf(aw, ux, v.x);
                v.y = fmaf(aw, uy, v.y);
                v.z = fmaf(aw, uz, v.z);
                v.w = fmaf(aw, uw, v.w);
            }
            aw *= aw;
        }
        // Write back to the same (wave-exclusive) column: no cross-wave
        // hazard between this wave's read and write, so no barrier here.
        Epad[m][w] = v;
    }
    __syncthreads();

    // Exclusive carry into chunk ch = inclusive scan at ch-1.
    float c0 = 0.f, c1 = 0.f, c2 = 0.f, c3 = 0.f;
    if (ch > 0) {
        float4 c4 = Epad[ch - 1][cq];
        c0 = c4.x; c1 = c4.y; c2 = c4.z; c3 = c4.w;
    }

    // Phase 3: fix up with carry and store (non-temporal: out is
    // write-once, keep it from evicting x in per-XCD L2).
    float p = a;
    #pragma unroll
    for (int t = 0; t < CH_; ++t) {
        float4 l = loc[t];
        f32x4 o;
        o.x = fmaf(c0, p, l.x);
        o.y = fmaf(c1, p, l.y);
        o.z = fmaf(c2, p, l.z);
        o.w = fmaf(c3, p, l.w);
        __builtin_nontemporal_store(o, &op[(size_t)t * jstride4]);
        p *= a;
    }
}

extern "C" void kernel_launch(void* const* d_in, const int* in_sizes, int n_in,
                              void* d_out, int out_size, void* d_ws, size_t ws_size,
                              hipStream_t stream) {
    const float* x   = (const float*)d_in[0];
    const float* A   = (const float*)d_in[1];
    float*       out = (float*)d_out;

    dim3 grid(B_ * D_);            // 256 blocks, one per (batch, r)
    dim3 block(NTHR_);             // 1024 threads = 16 waves
    hipLaunchKernelGGL(ssm_scan_kernel, grid, block, 0, stream, x, A, out);
}